// Round 1
// baseline (96.086 us; speedup 1.0000x reference)
//
#include <hip/hip_runtime.h>
#include <hip/hip_bf16.h>

#define RES_DIM 8192
#define BATCH   128
#define NNZ     1342177
#define LEAK    0.6f
#define BIAS    1.6f

// ---------------------------------------------------------------------------
// Kernel 1: transpose res_state [BATCH][RES_DIM] -> st [RES_DIM][BATCH]
// Classic 32x32 LDS tile, 32x8 threads, 4 rows per thread.
// ---------------------------------------------------------------------------
__global__ __launch_bounds__(256) void transpose_kernel(
    const float* __restrict__ in, float* __restrict__ out) {
    __shared__ float tile[32][33];
    int x = blockIdx.x * 32 + threadIdx.x;   // res_dim index
    int y = blockIdx.y * 32 + threadIdx.y;   // batch index
#pragma unroll
    for (int j = 0; j < 32; j += 8)
        tile[threadIdx.y + j][threadIdx.x] = in[(y + j) * RES_DIM + x];
    __syncthreads();
    x = blockIdx.y * 32 + threadIdx.x;       // batch index (out col)
    y = blockIdx.x * 32 + threadIdx.y;       // res_dim index (out row)
#pragma unroll
    for (int j = 0; j < 32; j += 8)
        out[(y + j) * BATCH + x] = tile[threadIdx.x][threadIdx.y + j];
}

// ---------------------------------------------------------------------------
// Kernel 2: row_start[i] = lower_bound(wr_rows, i), i in [0, RES_DIM]
// ---------------------------------------------------------------------------
__global__ __launch_bounds__(256) void rowptr_kernel(
    const int* __restrict__ rows, int* __restrict__ row_start) {
    int i = blockIdx.x * 256 + threadIdx.x;
    if (i > RES_DIM) return;
    int lo = 0, hi = NNZ;
    while (lo < hi) {
        int mid = (lo + hi) >> 1;
        if (rows[mid] < i) lo = mid + 1; else hi = mid;
    }
    row_start[i] = lo;
}

// ---------------------------------------------------------------------------
// Kernel 3: one block (128 threads) per output row r.
//   acc_b = sum_{k in row r} vals[k] * st[cols[k]][b]
//   out[b][r] = LEAK * tanh(acc_b + proj[b][r] + BIAS) + (1-LEAK)*res_state[b][r]
// vals/cols loads are wave-uniform (broadcast); st gather is coalesced 512B.
// ---------------------------------------------------------------------------
__global__ __launch_bounds__(128) void spmm_kernel(
    const float* __restrict__ vals, const int* __restrict__ cols,
    const int* __restrict__ row_start, const float* __restrict__ st,
    const float* __restrict__ proj, const float* __restrict__ res_state,
    float* __restrict__ out) {
    const int r = blockIdx.x;
    const int b = threadIdx.x;   // 0..127

    const int ks = row_start[r];
    const int ke = row_start[r + 1];

    float acc = 0.0f;
    int k = ks;
    // unrolled-by-4 main body (independent loads, FMA chain is fine)
    for (; k + 4 <= ke; k += 4) {
        int   c0 = cols[k + 0], c1 = cols[k + 1], c2 = cols[k + 2], c3 = cols[k + 3];
        float v0 = vals[k + 0], v1 = vals[k + 1], v2 = vals[k + 2], v3 = vals[k + 3];
        acc += v0 * st[c0 * BATCH + b];
        acc += v1 * st[c1 * BATCH + b];
        acc += v2 * st[c2 * BATCH + b];
        acc += v3 * st[c3 * BATCH + b];
    }
    for (; k < ke; ++k) {
        acc += vals[k] * st[cols[k] * BATCH + b];
    }

    const int oi = b * RES_DIM + r;
    float yv = acc + proj[oi] + BIAS;
    float t  = tanhf(yv);
    out[oi] = LEAK * t + (1.0f - LEAK) * res_state[oi];
}

// ---------------------------------------------------------------------------
extern "C" void kernel_launch(void* const* d_in, const int* in_sizes, int n_in,
                              void* d_out, int out_size, void* d_ws, size_t ws_size,
                              hipStream_t stream) {
    const float* proj      = (const float*)d_in[0];   // [BATCH][RES_DIM]
    const float* res_state = (const float*)d_in[1];   // [BATCH][RES_DIM]
    const float* wr_vals   = (const float*)d_in[2];   // [NNZ]
    const int*   wr_rows   = (const int*)d_in[3];     // [NNZ], sorted
    const int*   wr_cols   = (const int*)d_in[4];     // [NNZ]
    float*       out       = (float*)d_out;           // [BATCH][RES_DIM]

    // Workspace layout: st [RES_DIM][BATCH] f32 (4 MB), row_start (RES_DIM+1) i32
    float* st        = (float*)d_ws;
    int*   row_start = (int*)((char*)d_ws + (size_t)RES_DIM * BATCH * sizeof(float));

    dim3 tgrid(RES_DIM / 32, BATCH / 32);
    dim3 tblock(32, 8);
    transpose_kernel<<<tgrid, tblock, 0, stream>>>(res_state, st);

    rowptr_kernel<<<(RES_DIM + 1 + 255) / 256, 256, 0, stream>>>(wr_rows, row_start);

    spmm_kernel<<<RES_DIM, 128, 0, stream>>>(wr_vals, wr_cols, row_start, st,
                                             proj, res_state, out);
}

// Round 2
// 56.272 us; speedup vs baseline: 1.7075x; 1.7075x over previous
//
#include <hip/hip_runtime.h>
#include <hip/hip_bf16.h>
#include <stdint.h>

#define RES_DIM 8192
#define BATCH   128
#define NPAIR   64          // BATCH/2 (bf16 pairs per table row)
#define NNZ     1342177
#define LEAK    0.6f
#define BIAS    1.6f

// ---------------------------------------------------------------------------
// helpers
// ---------------------------------------------------------------------------
__device__ __forceinline__ float fast_tanh(float x) {
    // tanh(x) = 1 - 2/(e^{2x}+1); handles +-inf saturation correctly.
    float e = __expf(2.0f * x);
    return 1.0f - 2.0f / (e + 1.0f);
}

__device__ __forceinline__ uint32_t f32_to_bf16_rne(float f) {
    uint32_t u = __float_as_uint(f);
    return (u + 0x7fffu + ((u >> 16) & 1u)) >> 16;
}

// ---------------------------------------------------------------------------
// Kernel 1: res_state [BATCH][RES_DIM] f32 -> st2 [RES_DIM][NPAIR] u32
//           (each u32 packs bf16 of batches (2p, 2p+1); lo = even batch)
// ---------------------------------------------------------------------------
__global__ __launch_bounds__(256) void conv_kernel(
    const float* __restrict__ in, uint32_t* __restrict__ st2) {
    __shared__ float tile[32][33];
    const int r0 = blockIdx.x * 32;
    const int b0 = blockIdx.y * 32;
    const int tx = threadIdx.x, ty = threadIdx.y;   // 32x8
#pragma unroll
    for (int j = 0; j < 32; j += 8)
        tile[ty + j][tx] = in[(size_t)(b0 + ty + j) * RES_DIM + r0 + tx];
    __syncthreads();
    const int t = ty * 32 + tx;
#pragma unroll
    for (int i = t; i < 512; i += 256) {            // 32 r x 16 pairs
        int rl = i >> 4, pl = i & 15;
        uint32_t lo = f32_to_bf16_rne(tile[2 * pl + 0][rl]);
        uint32_t hi = f32_to_bf16_rne(tile[2 * pl + 1][rl]);
        st2[(size_t)(r0 + rl) * NPAIR + (b0 >> 1) + pl] = lo | (hi << 16);
    }
}

// ---------------------------------------------------------------------------
// Kernel 2: row_start[i] = lower_bound(wr_rows, i)
// ---------------------------------------------------------------------------
__global__ __launch_bounds__(256) void rowptr_kernel(
    const int* __restrict__ rows, int* __restrict__ row_start) {
    int i = blockIdx.x * 256 + threadIdx.x;
    if (i > RES_DIM) return;
    int lo = 0, hi = NNZ;
    while (lo < hi) {
        int mid = (lo + hi) >> 1;
        if (rows[mid] < i) lo = mid + 1; else hi = mid;
    }
    row_start[i] = lo;
}

// ---------------------------------------------------------------------------
// Kernel 3: 4 waves/block, one row per wave; lane l holds batches 2l, 2l+1.
// Gather is one coalesced 256B line per nnz; vals/cols via uniform
// int4/float4 broadcast loads. Writes yT[r][b] coalesced.
// ---------------------------------------------------------------------------
template <int BF16Y>
__global__ __launch_bounds__(256) void spmm_kernel(
    const float* __restrict__ vals, const int* __restrict__ cols,
    const int* __restrict__ row_start, const uint32_t* __restrict__ stb,
    void* __restrict__ yT) {
    const int l = threadIdx.x & 63;
    const int r = blockIdx.x * 4 + (threadIdx.x >> 6);

    const int ks = row_start[r];
    const int ke = row_start[r + 1];

    float acc0 = 0.0f, acc1 = 0.0f;
    int k = ks;
    // peel to 16B alignment for the int4/float4 body
    while (k < ke && (k & 3)) {
        int c = cols[k]; float v = vals[k];
        uint32_t g = stb[(size_t)c * NPAIR + l];
        acc0 = fmaf(v, __uint_as_float(g << 16), acc0);
        acc1 = fmaf(v, __uint_as_float(g & 0xffff0000u), acc1);
        ++k;
    }
#pragma unroll 2
    for (; k + 4 <= ke; k += 4) {
        int4   c = *(const int4*)(cols + k);
        float4 v = *(const float4*)(vals + k);
        uint32_t g0 = stb[(size_t)c.x * NPAIR + l];
        uint32_t g1 = stb[(size_t)c.y * NPAIR + l];
        uint32_t g2 = stb[(size_t)c.z * NPAIR + l];
        uint32_t g3 = stb[(size_t)c.w * NPAIR + l];
        acc0 = fmaf(v.x, __uint_as_float(g0 << 16), acc0);
        acc1 = fmaf(v.x, __uint_as_float(g0 & 0xffff0000u), acc1);
        acc0 = fmaf(v.y, __uint_as_float(g1 << 16), acc0);
        acc1 = fmaf(v.y, __uint_as_float(g1 & 0xffff0000u), acc1);
        acc0 = fmaf(v.z, __uint_as_float(g2 << 16), acc0);
        acc1 = fmaf(v.z, __uint_as_float(g2 & 0xffff0000u), acc1);
        acc0 = fmaf(v.w, __uint_as_float(g3 << 16), acc0);
        acc1 = fmaf(v.w, __uint_as_float(g3 & 0xffff0000u), acc1);
    }
    for (; k < ke; ++k) {
        int c = cols[k]; float v = vals[k];
        uint32_t g = stb[(size_t)c * NPAIR + l];
        acc0 = fmaf(v, __uint_as_float(g << 16), acc0);
        acc1 = fmaf(v, __uint_as_float(g & 0xffff0000u), acc1);
    }

    if (BF16Y) {
        uint32_t p = f32_to_bf16_rne(acc0) | (f32_to_bf16_rne(acc1) << 16);
        ((uint32_t*)yT)[(size_t)r * NPAIR + l] = p;
    } else {
        *(float2*)((float*)yT + (size_t)r * BATCH + 2 * l) = make_float2(acc0, acc1);
    }
}

// ---------------------------------------------------------------------------
// Kernel 4: epilogue with 32x32 LDS transpose; all global I/O coalesced.
//   out[b][r] = LEAK*tanh(yT[r][b] + proj[b][r] + BIAS) + (1-LEAK)*res[b][r]
// ---------------------------------------------------------------------------
template <int BF16Y>
__global__ __launch_bounds__(256) void epi_kernel(
    const void* __restrict__ yT, const float* __restrict__ proj,
    const float* __restrict__ res, float* __restrict__ out) {
    __shared__ float tile[32][33];
    const int r0 = blockIdx.x * 32;
    const int b0 = blockIdx.y * 32;
    const int tx = threadIdx.x, ty = threadIdx.y;   // 32x8
#pragma unroll
    for (int j = 0; j < 32; j += 8) {
        size_t idx = (size_t)(r0 + ty + j) * BATCH + b0 + tx;
        float v;
        if (BF16Y) {
            uint32_t u = ((const uint16_t*)yT)[idx];
            v = __uint_as_float(u << 16);
        } else {
            v = ((const float*)yT)[idx];
        }
        tile[ty + j][tx] = v;
    }
    __syncthreads();
#pragma unroll
    for (int j = 0; j < 32; j += 8) {
        size_t oi = (size_t)(b0 + ty + j) * RES_DIM + r0 + tx;
        float y = tile[tx][ty + j] + proj[oi] + BIAS;
        out[oi] = LEAK * fast_tanh(y) + (1.0f - LEAK) * res[oi];
    }
}

// ---------------------------------------------------------------------------
extern "C" void kernel_launch(void* const* d_in, const int* in_sizes, int n_in,
                              void* d_out, int out_size, void* d_ws, size_t ws_size,
                              hipStream_t stream) {
    const float* proj      = (const float*)d_in[0];
    const float* res_state = (const float*)d_in[1];
    const float* wr_vals   = (const float*)d_in[2];
    const int*   wr_rows   = (const int*)d_in[3];
    const int*   wr_cols   = (const int*)d_in[4];
    float*       out       = (float*)d_out;

    // ws layout: st2 (2 MB) | row_start (32.8 KB) | yT (4 MB f32 or 2 MB bf16)
    uint8_t*  ws        = (uint8_t*)d_ws;
    uint32_t* st2       = (uint32_t*)ws;
    int*      row_start = (int*)(ws + 2097152);
    uint8_t*  yT        = ws + 2130176;                 // 256B-aligned
    const bool f32y = ws_size >= (2130176ull + (size_t)RES_DIM * BATCH * 4);

    conv_kernel<<<dim3(RES_DIM / 32, BATCH / 32), dim3(32, 8), 0, stream>>>(res_state, st2);
    rowptr_kernel<<<(RES_DIM + 256) / 256, 256, 0, stream>>>(wr_rows, row_start);

    if (f32y) {
        spmm_kernel<0><<<RES_DIM / 4, 256, 0, stream>>>(wr_vals, wr_cols, row_start, st2, yT);
        epi_kernel<0><<<dim3(RES_DIM / 32, BATCH / 32), dim3(32, 8), 0, stream>>>(yT, proj, res_state, out);
    } else {
        spmm_kernel<1><<<RES_DIM / 4, 256, 0, stream>>>(wr_vals, wr_cols, row_start, st2, yT);
        epi_kernel<1><<<dim3(RES_DIM / 32, BATCH / 32), dim3(32, 8), 0, stream>>>(yT, proj, res_state, out);
    }
}

// Round 3
// 36.463 us; speedup vs baseline: 2.6352x; 1.5433x over previous
//
#include <hip/hip_runtime.h>
#include <hip/hip_bf16.h>
#include <stdint.h>

#define RES_DIM 8192
#define BATCH   128
#define NNZ     1342177
#define LEAK    0.6f
#define BIAS    1.6f

#define CONV_BLOCKS 1024                 // (RES_DIM/32) * (BATCH/32)
#define BND_BLOCKS  ((NNZ + 255) / 256)  // 5244

// ---------------------------------------------------------------------------
// helpers
// ---------------------------------------------------------------------------
__device__ __forceinline__ float fast_tanh(float x) {
    float e = __expf(2.0f * x);
    return 1.0f - 2.0f / (e + 1.0f);
}

__device__ __forceinline__ uint32_t f32_to_bf16_rne(float f) {
    uint32_t u = __float_as_uint(f);
    return (u + 0x7fffu + ((u >> 16) & 1u)) >> 16;
}

// ---------------------------------------------------------------------------
// Kernel 1 (fused prep):
//  blocks [0, CONV_BLOCKS):  res_state [B][R] f32 -> st2 [R][64] u32
//                            (u32 packs bf16 of batches (2p, 2p+1), lo = even)
//  blocks [CONV_BLOCKS, +BND_BLOCKS): row_start from sorted rows via
//                            boundary detection (coalesced stream, no bsearch)
// ---------------------------------------------------------------------------
__global__ __launch_bounds__(256) void prep_kernel(
    const float* __restrict__ in, uint32_t* __restrict__ st2,
    const int* __restrict__ rows, int* __restrict__ row_start) {
    if (blockIdx.x < CONV_BLOCKS) {
        __shared__ float tile[32][33];
        const int bx = blockIdx.x & 255;     // r-tile
        const int by = blockIdx.x >> 8;      // b-tile
        const int tx = threadIdx.x & 31, ty = threadIdx.x >> 5;  // 32x8
        const int r0 = bx * 32, b0 = by * 32;
#pragma unroll
        for (int j = 0; j < 32; j += 8)
            tile[ty + j][tx] = in[(size_t)(b0 + ty + j) * RES_DIM + r0 + tx];
        __syncthreads();
        const int t = threadIdx.x;
#pragma unroll
        for (int i = t; i < 512; i += 256) {          // 32 r x 16 pairs
            int rl = i >> 4, pl = i & 15;
            uint32_t lo = f32_to_bf16_rne(tile[2 * pl + 0][rl]);
            uint32_t hi = f32_to_bf16_rne(tile[2 * pl + 1][rl]);
            st2[(size_t)(r0 + rl) * 64 + (b0 >> 1) + pl] = lo | (hi << 16);
        }
    } else {
        const int k = (blockIdx.x - CONV_BLOCKS) * 256 + threadIdx.x;
        if (k >= NNZ) return;
        const int r1 = rows[k];
        if (k == 0)
            for (int r = 0; r <= r1; ++r) row_start[r] = 0;
        if (k + 1 < NNZ) {
            const int r2 = rows[k + 1];
            for (int r = r1 + 1; r <= r2; ++r) row_start[r] = k + 1;
        } else {
            for (int r = r1 + 1; r <= RES_DIM; ++r) row_start[r] = NNZ;
        }
    }
}

// ---------------------------------------------------------------------------
// Kernel 2: spmm. One wave per row; 16-lane group g handles nnz k+4i+g,
// lane j = l&15 holds batches 8j..8j+7 (one uint4 = 8 bf16 per gather).
// One dwordx4 gather retires 4 nnz (1 KB/wave). Cross-group reduce via
// 2x shfl_xor at the end.
// ---------------------------------------------------------------------------
#define FMA8(G, v)                                            \
    do {                                                      \
        a0 = fmaf(v, __uint_as_float((G).x << 16), a0);       \
        a1 = fmaf(v, __uint_as_float((G).x & 0xffff0000u), a1); \
        a2 = fmaf(v, __uint_as_float((G).y << 16), a2);       \
        a3 = fmaf(v, __uint_as_float((G).y & 0xffff0000u), a3); \
        a4 = fmaf(v, __uint_as_float((G).z << 16), a4);       \
        a5 = fmaf(v, __uint_as_float((G).z & 0xffff0000u), a5); \
        a6 = fmaf(v, __uint_as_float((G).w << 16), a6);       \
        a7 = fmaf(v, __uint_as_float((G).w & 0xffff0000u), a7); \
    } while (0)

template <int BF16Y>
__global__ __launch_bounds__(256, 8) void spmm_kernel(
    const float* __restrict__ vals, const int* __restrict__ cols,
    const int* __restrict__ row_start, const uint32_t* __restrict__ st2,
    void* __restrict__ yT) {
    const int l = threadIdx.x & 63;
    const int g = l >> 4;          // nnz sub-slot within a 4-group
    const int j = l & 15;          // batch slot: batches 8j..8j+7
    const int r = blockIdx.x * 4 + (threadIdx.x >> 6);

    const int ks = row_start[r];
    const int ke = row_start[r + 1];

    float a0 = 0, a1 = 0, a2 = 0, a3 = 0, a4 = 0, a5 = 0, a6 = 0, a7 = 0;
    const uint32_t* tp = st2 + j * 4;   // + c*64 per gather

    int k = ks;
    for (; k + 16 <= ke; k += 16) {
        const int k0 = k + g, k1 = k + 4 + g, k2 = k + 8 + g, k3 = k + 12 + g;
        const int c0 = cols[k0], c1 = cols[k1], c2 = cols[k2], c3 = cols[k3];
        const float v0 = vals[k0], v1 = vals[k1], v2 = vals[k2], v3 = vals[k3];
        const uint4 G0 = *(const uint4*)(tp + (size_t)c0 * 64);
        const uint4 G1 = *(const uint4*)(tp + (size_t)c1 * 64);
        const uint4 G2 = *(const uint4*)(tp + (size_t)c2 * 64);
        const uint4 G3 = *(const uint4*)(tp + (size_t)c3 * 64);
        FMA8(G0, v0);
        FMA8(G1, v1);
        FMA8(G2, v2);
        FMA8(G3, v3);
    }
    if (k < ke) {
#pragma unroll
        for (int i = 0; i < 4; ++i) {
            const int kk = k + 4 * i + g;
            int c = 0;
            float v = 0.0f;
            if (kk < ke) { c = cols[kk]; v = vals[kk]; }  // exec-masked loads
            const uint4 G = *(const uint4*)(tp + (size_t)c * 64);
            FMA8(G, v);
        }
    }

    // combine the 4 nnz-groups: lanes j, j+16, j+32, j+48 hold partials
    a0 += __shfl_xor(a0, 16, 64); a0 += __shfl_xor(a0, 32, 64);
    a1 += __shfl_xor(a1, 16, 64); a1 += __shfl_xor(a1, 32, 64);
    a2 += __shfl_xor(a2, 16, 64); a2 += __shfl_xor(a2, 32, 64);
    a3 += __shfl_xor(a3, 16, 64); a3 += __shfl_xor(a3, 32, 64);
    a4 += __shfl_xor(a4, 16, 64); a4 += __shfl_xor(a4, 32, 64);
    a5 += __shfl_xor(a5, 16, 64); a5 += __shfl_xor(a5, 32, 64);
    a6 += __shfl_xor(a6, 16, 64); a6 += __shfl_xor(a6, 32, 64);
    a7 += __shfl_xor(a7, 16, 64); a7 += __shfl_xor(a7, 32, 64);

    if (l < 16) {
        if (BF16Y) {
            uint32_t* o = (uint32_t*)yT + (size_t)r * 64 + j * 4;
            o[0] = f32_to_bf16_rne(a0) | (f32_to_bf16_rne(a1) << 16);
            o[1] = f32_to_bf16_rne(a2) | (f32_to_bf16_rne(a3) << 16);
            o[2] = f32_to_bf16_rne(a4) | (f32_to_bf16_rne(a5) << 16);
            o[3] = f32_to_bf16_rne(a6) | (f32_to_bf16_rne(a7) << 16);
        } else {
            float* o = (float*)yT + (size_t)r * BATCH + j * 8;
            *(float4*)(o + 0) = make_float4(a0, a1, a2, a3);
            *(float4*)(o + 4) = make_float4(a4, a5, a6, a7);
        }
    }
}

// ---------------------------------------------------------------------------
// Kernel 3: epilogue with 32x32 LDS transpose; all global I/O coalesced.
// ---------------------------------------------------------------------------
template <int BF16Y>
__global__ __launch_bounds__(256) void epi_kernel(
    const void* __restrict__ yT, const float* __restrict__ proj,
    const float* __restrict__ res, float* __restrict__ out) {
    __shared__ float tile[32][33];
    const int r0 = blockIdx.x * 32;
    const int b0 = blockIdx.y * 32;
    const int tx = threadIdx.x, ty = threadIdx.y;   // 32x8
#pragma unroll
    for (int jj = 0; jj < 32; jj += 8) {
        size_t idx = (size_t)(r0 + ty + jj) * BATCH + b0 + tx;
        float v;
        if (BF16Y) {
            uint32_t u = ((const uint16_t*)yT)[idx];
            v = __uint_as_float(u << 16);
        } else {
            v = ((const float*)yT)[idx];
        }
        tile[ty + jj][tx] = v;
    }
    __syncthreads();
#pragma unroll
    for (int jj = 0; jj < 32; jj += 8) {
        size_t oi = (size_t)(b0 + ty + jj) * RES_DIM + r0 + tx;
        float y = tile[tx][ty + jj] + proj[oi] + BIAS;
        out[oi] = LEAK * fast_tanh(y) + (1.0f - LEAK) * res[oi];
    }
}

// ---------------------------------------------------------------------------
extern "C" void kernel_launch(void* const* d_in, const int* in_sizes, int n_in,
                              void* d_out, int out_size, void* d_ws, size_t ws_size,
                              hipStream_t stream) {
    const float* proj      = (const float*)d_in[0];
    const float* res_state = (const float*)d_in[1];
    const float* wr_vals   = (const float*)d_in[2];
    const int*   wr_rows   = (const int*)d_in[3];
    const int*   wr_cols   = (const int*)d_in[4];
    float*       out       = (float*)d_out;

    // ws layout: st2 (2 MB) | row_start (32.8 KB) | yT (4 MB f32 or 2 MB bf16)
    uint8_t*  ws        = (uint8_t*)d_ws;
    uint32_t* st2       = (uint32_t*)ws;
    int*      row_start = (int*)(ws + 2097152);
    uint8_t*  yT        = ws + 2130176;
    const bool f32y = ws_size >= (2130176ull + (size_t)RES_DIM * BATCH * 4);

    prep_kernel<<<CONV_BLOCKS + BND_BLOCKS, 256, 0, stream>>>(
        res_state, st2, wr_rows, row_start);

    if (f32y) {
        spmm_kernel<0><<<RES_DIM / 4, 256, 0, stream>>>(wr_vals, wr_cols, row_start, st2, yT);
        epi_kernel<0><<<dim3(RES_DIM / 32, BATCH / 32), dim3(32, 8), 0, stream>>>(yT, proj, res_state, out);
    } else {
        spmm_kernel<1><<<RES_DIM / 4, 256, 0, stream>>>(wr_vals, wr_cols, row_start, st2, yT);
        epi_kernel<1><<<dim3(RES_DIM / 32, BATCH / 32), dim3(32, 8), 0, stream>>>(yT, proj, res_state, out);
    }
}

// Round 4
// 35.793 us; speedup vs baseline: 2.6845x; 1.0187x over previous
//
#include <hip/hip_runtime.h>
#include <hip/hip_bf16.h>
#include <stdint.h>

#define RES_DIM 8192
#define BATCH   128
#define NNZ     1342177
#define LEAK    0.6f
#define BIAS    1.6f

#define CONV_BLOCKS 1024                          // (RES_DIM/32) * (BATCH/32)
#define BND_THREADS ((NNZ + 3) / 4)               // 335545
#define BND_BLOCKS  ((BND_THREADS + 255) / 256)   // 1311

// ---------------------------------------------------------------------------
// helpers
// ---------------------------------------------------------------------------
__device__ __forceinline__ float fast_tanh(float x) {
    float e = __expf(2.0f * x);
    return 1.0f - 2.0f / (e + 1.0f);
}

__device__ __forceinline__ uint32_t f32_to_bf16_rne(float f) {
    uint32_t u = __float_as_uint(f);
    return (u + 0x7fffu + ((u >> 16) & 1u)) >> 16;
}

// ---------------------------------------------------------------------------
// Kernel 1 (fused prep):
//  blocks [0, CONV_BLOCKS): res_state [B][R] f32 -> st2 [R][64] u32
//                           (u32 p packs bf16 of batches (2p, 2p+1), lo = even)
//  blocks [CONV_BLOCKS, +BND_BLOCKS): row_start via int4 boundary detection
// ---------------------------------------------------------------------------
__global__ __launch_bounds__(256) void prep_kernel(
    const float* __restrict__ in, uint32_t* __restrict__ st2,
    const int* __restrict__ rows, int* __restrict__ row_start) {
    if (blockIdx.x < CONV_BLOCKS) {
        __shared__ float tile[32][33];
        const int bx = blockIdx.x & 255;     // r-tile
        const int by = blockIdx.x >> 8;      // b-tile
        const int tx = threadIdx.x & 31, ty = threadIdx.x >> 5;  // 32x8
        const int r0 = bx * 32, b0 = by * 32;
#pragma unroll
        for (int j = 0; j < 32; j += 8)
            tile[ty + j][tx] = in[(size_t)(b0 + ty + j) * RES_DIM + r0 + tx];
        __syncthreads();
#pragma unroll
        for (int i = threadIdx.x; i < 512; i += 256) {   // 32 r x 16 pairs
            int rl = i >> 4, pl = i & 15;
            uint32_t lo = f32_to_bf16_rne(tile[2 * pl + 0][rl]);
            uint32_t hi = f32_to_bf16_rne(tile[2 * pl + 1][rl]);
            st2[(size_t)(r0 + rl) * 64 + (b0 >> 1) + pl] = lo | (hi << 16);
        }
    } else {
        const int t  = (blockIdx.x - CONV_BLOCKS) * 256 + threadIdx.x;
        const int k4 = t * 4;
        if (k4 >= NNZ) return;
        if (k4 + 4 <= NNZ) {                 // full int4 (k4+4 <= NNZ-1 since NNZ%4==1)
            const int4 R = *(const int4*)(rows + k4);
            if (k4 == 0)
                for (int r = 0; r <= R.x; ++r) row_start[r] = 0;
            const int rn = rows[k4 + 4];
            for (int r = R.x + 1; r <= R.y; ++r) row_start[r] = k4 + 1;
            for (int r = R.y + 1; r <= R.z; ++r) row_start[r] = k4 + 2;
            for (int r = R.z + 1; r <= R.w; ++r) row_start[r] = k4 + 3;
            for (int r = R.w + 1; r <= rn;  ++r) row_start[r] = k4 + 4;
        } else {                             // k4 == NNZ-1 exactly
            const int r1 = rows[k4];
            for (int r = r1 + 1; r <= RES_DIM; ++r) row_start[r] = NNZ;
        }
    }
}

// ---------------------------------------------------------------------------
// Kernel 2: spmm. One BLOCK (4 waves) per row; wave w takes 16-nnz units
// w, w+4, w+8, ... . Within a wave, 16-lane group g owns 4 contiguous nnz
// (one int4/float4 broadcast load); lane j = l&15 holds batches 8j..8j+7
// (one uint4 = 8 bf16 per gather; 4 nnz retired per gather instruction).
// Partials: shfl-reduce across groups, LDS-reduce across waves.
// ---------------------------------------------------------------------------
#define FMA8(G, v)                                              \
    do {                                                        \
        a0 = fmaf(v, __uint_as_float((G).x << 16), a0);         \
        a1 = fmaf(v, __uint_as_float((G).x & 0xffff0000u), a1); \
        a2 = fmaf(v, __uint_as_float((G).y << 16), a2);         \
        a3 = fmaf(v, __uint_as_float((G).y & 0xffff0000u), a3); \
        a4 = fmaf(v, __uint_as_float((G).z << 16), a4);         \
        a5 = fmaf(v, __uint_as_float((G).z & 0xffff0000u), a5); \
        a6 = fmaf(v, __uint_as_float((G).w << 16), a6);         \
        a7 = fmaf(v, __uint_as_float((G).w & 0xffff0000u), a7); \
    } while (0)

template <int BF16Y>
__global__ __launch_bounds__(256, 8) void spmm_kernel(
    const float* __restrict__ vals, const int* __restrict__ cols,
    const int* __restrict__ row_start, const uint32_t* __restrict__ st2,
    void* __restrict__ yT) {
    const int t = threadIdx.x;
    const int w = t >> 6;          // wave 0..3
    const int l = t & 63;
    const int g = l >> 4;          // 4-nnz pack within a unit
    const int j = l & 15;          // batch slot: batches 8j..8j+7
    // XCD-bijective swizzle: 8192 % 8 == 0 -> each XCD gets 1024 contiguous rows
    const int r = (blockIdx.x & 7) * (RES_DIM / 8) + (blockIdx.x >> 3);

    const int ks = row_start[r];
    const int ke = row_start[r + 1];
    const int ka = min(ke, (ks + 3) & ~3);   // 16B-align start for int4 loads
    const int U  = (ke - ka) >> 4;           // full 16-nnz units
    const int ts = ka + (U << 4);            // tail start (<16 left)

    const uint32_t* tp = st2 + j * 4;
    float a0 = 0, a1 = 0, a2 = 0, a3 = 0, a4 = 0, a5 = 0, a6 = 0, a7 = 0;

    // head (<=3 nnz, unaligned) on wave 0
    if (w == 0 && ks < ka) {
        const int kk = ks + g;
        int c = 0; float v = 0.0f;
        if (kk < ka) { c = cols[kk]; v = vals[kk]; }
        const uint4 G = *(const uint4*)(tp + (size_t)c * 64);
        FMA8(G, v);
    }
    // tail (<=15 nnz) on wave 1
    if (w == 1 && ts < ke) {
#pragma unroll
        for (int i = 0; i < 4; ++i) {
            const int kk = ts + 4 * i + g;
            int c = 0; float v = 0.0f;
            if (kk < ke) { c = cols[kk]; v = vals[kk]; }
            const uint4 G = *(const uint4*)(tp + (size_t)c * 64);
            FMA8(G, v);
        }
    }
    // main units, strided across the 4 waves
    for (int u = w; u < U; u += 4) {
        const int base = ka + (u << 4) + 4 * g;
        const int4   C = *(const int4*)(cols + base);
        const float4 V = *(const float4*)(vals + base);
        const uint4 G0 = *(const uint4*)(tp + (size_t)C.x * 64);
        const uint4 G1 = *(const uint4*)(tp + (size_t)C.y * 64);
        const uint4 G2 = *(const uint4*)(tp + (size_t)C.z * 64);
        const uint4 G3 = *(const uint4*)(tp + (size_t)C.w * 64);
        FMA8(G0, V.x);
        FMA8(G1, V.y);
        FMA8(G2, V.z);
        FMA8(G3, V.w);
    }

    // combine the 4 nnz-groups within the wave
    a0 += __shfl_xor(a0, 16, 64); a0 += __shfl_xor(a0, 32, 64);
    a1 += __shfl_xor(a1, 16, 64); a1 += __shfl_xor(a1, 32, 64);
    a2 += __shfl_xor(a2, 16, 64); a2 += __shfl_xor(a2, 32, 64);
    a3 += __shfl_xor(a3, 16, 64); a3 += __shfl_xor(a3, 32, 64);
    a4 += __shfl_xor(a4, 16, 64); a4 += __shfl_xor(a4, 32, 64);
    a5 += __shfl_xor(a5, 16, 64); a5 += __shfl_xor(a5, 32, 64);
    a6 += __shfl_xor(a6, 16, 64); a6 += __shfl_xor(a6, 32, 64);
    a7 += __shfl_xor(a7, 16, 64); a7 += __shfl_xor(a7, 32, 64);

    // combine across the 4 waves via LDS
    __shared__ float red[4][16][8];
    if (l < 16) {
        *(float4*)&red[w][j][0] = make_float4(a0, a1, a2, a3);
        *(float4*)&red[w][j][4] = make_float4(a4, a5, a6, a7);
    }
    __syncthreads();
    if (t < BATCH) {                     // thread t owns batch b = t
        const int jj = t >> 3, ii = t & 7;
        float s = red[0][jj][ii] + red[1][jj][ii] + red[2][jj][ii] + red[3][jj][ii];
        if (BF16Y) {
            float shi = __shfl_down(s, 1, 64);
            if (!(t & 1))
                ((uint32_t*)yT)[(size_t)r * 64 + (t >> 1)] =
                    f32_to_bf16_rne(s) | (f32_to_bf16_rne(shi) << 16);
        } else {
            ((float*)yT)[(size_t)r * BATCH + t] = s;
        }
    }
}

// ---------------------------------------------------------------------------
// Kernel 3: epilogue, 64r x 32b tiles, float4 everywhere.
//   out[b][r] = LEAK*tanh(yT[r][b] + proj[b][r] + BIAS) + (1-LEAK)*res[b][r]
// ---------------------------------------------------------------------------
template <int BF16Y>
__global__ __launch_bounds__(256) void epi_kernel(
    const void* __restrict__ yT, const float* __restrict__ proj,
    const float* __restrict__ res, float* __restrict__ out) {
    __shared__ float tile[64][33];
    const int r0 = blockIdx.x * 64;
    const int b0 = blockIdx.y * 32;
    const int t  = threadIdx.x;
#pragma unroll
    for (int p = 0; p < 2; ++p) {            // load 32 r per pass
        const int rl = p * 32 + (t >> 3);
        const int bq = (t & 7) * 4;
        float x, y, z, wv;
        if (BF16Y) {
            ushort4 u = *(const ushort4*)((const uint16_t*)yT +
                         (size_t)(r0 + rl) * BATCH + b0 + bq);
            x  = __uint_as_float((uint32_t)u.x << 16);
            y  = __uint_as_float((uint32_t)u.y << 16);
            z  = __uint_as_float((uint32_t)u.z << 16);
            wv = __uint_as_float((uint32_t)u.w << 16);
        } else {
            float4 v = *(const float4*)((const float*)yT +
                         (size_t)(r0 + rl) * BATCH + b0 + bq);
            x = v.x; y = v.y; z = v.z; wv = v.w;
        }
        tile[rl][bq + 0] = x; tile[rl][bq + 1] = y;
        tile[rl][bq + 2] = z; tile[rl][bq + 3] = wv;
    }
    __syncthreads();
#pragma unroll
    for (int p = 0; p < 2; ++p) {            // store 16 b per pass
        const int bl = p * 16 + (t >> 4);
        const int rq = (t & 15) * 4;
        const size_t oi = (size_t)(b0 + bl) * RES_DIM + r0 + rq;
        const float4 pj = *(const float4*)(proj + oi);
        const float4 rs = *(const float4*)(res + oi);
        float4 o;
        o.x = LEAK * fast_tanh(tile[rq + 0][bl] + pj.x + BIAS) + (1.0f - LEAK) * rs.x;
        o.y = LEAK * fast_tanh(tile[rq + 1][bl] + pj.y + BIAS) + (1.0f - LEAK) * rs.y;
        o.z = LEAK * fast_tanh(tile[rq + 2][bl] + pj.z + BIAS) + (1.0f - LEAK) * rs.z;
        o.w = LEAK * fast_tanh(tile[rq + 3][bl] + pj.w + BIAS) + (1.0f - LEAK) * rs.w;
        *(float4*)(out + oi) = o;
    }
}

// ---------------------------------------------------------------------------
extern "C" void kernel_launch(void* const* d_in, const int* in_sizes, int n_in,
                              void* d_out, int out_size, void* d_ws, size_t ws_size,
                              hipStream_t stream) {
    const float* proj      = (const float*)d_in[0];
    const float* res_state = (const float*)d_in[1];
    const float* wr_vals   = (const float*)d_in[2];
    const int*   wr_rows   = (const int*)d_in[3];
    const int*   wr_cols   = (const int*)d_in[4];
    float*       out       = (float*)d_out;

    // ws layout: st2 (2 MB) | row_start (32.8 KB) | yT (4 MB f32 or 2 MB bf16)
    uint8_t*  ws        = (uint8_t*)d_ws;
    uint32_t* st2       = (uint32_t*)ws;
    int*      row_start = (int*)(ws + 2097152);
    uint8_t*  yT        = ws + 2130176;
    const bool f32y = ws_size >= (2130176ull + (size_t)RES_DIM * BATCH * 4);

    prep_kernel<<<CONV_BLOCKS + BND_BLOCKS, 256, 0, stream>>>(
        res_state, st2, wr_rows, row_start);

    if (f32y) {
        spmm_kernel<0><<<RES_DIM, 256, 0, stream>>>(wr_vals, wr_cols, row_start, st2, yT);
        epi_kernel<0><<<dim3(RES_DIM / 64, BATCH / 32), 256, 0, stream>>>(yT, proj, res_state, out);
    } else {
        spmm_kernel<1><<<RES_DIM, 256, 0, stream>>>(wr_vals, wr_cols, row_start, st2, yT);
        epi_kernel<1><<<dim3(RES_DIM / 64, BATCH / 32), 256, 0, stream>>>(yT, proj, res_state, out);
    }
}

// Round 5
// 35.523 us; speedup vs baseline: 2.7049x; 1.0076x over previous
//
#include <hip/hip_runtime.h>
#include <hip/hip_bf16.h>
#include <stdint.h>

#define RES_DIM 8192
#define BATCH   128
#define NNZ     1342177
#define LEAK    0.6f
#define BIAS    1.6f

#define CONV_BLOCKS 1024                          // (RES_DIM/32) * (BATCH/32)
#define BND_THREADS ((NNZ + 3) / 4)               // 335545
#define BND_BLOCKS  ((BND_THREADS + 255) / 256)   // 1311

// ---------------------------------------------------------------------------
// helpers
// ---------------------------------------------------------------------------
__device__ __forceinline__ float fast_tanh(float x) {
    float e = __expf(2.0f * x);
    return 1.0f - 2.0f / (e + 1.0f);
}

__device__ __forceinline__ uint32_t f32_to_bf16_rne(float f) {
    uint32_t u = __float_as_uint(f);
    return (u + 0x7fffu + ((u >> 16) & 1u)) >> 16;
}

// ---------------------------------------------------------------------------
// Kernel 1 (fused prep):
//  blocks [0, CONV_BLOCKS): res_state [B][R] f32 -> st2 [R][64] u32
//                           (u32 p packs bf16 of batches (2p, 2p+1), lo = even)
//  blocks [CONV_BLOCKS, +BND_BLOCKS): row_start via int4 boundary detection
// ---------------------------------------------------------------------------
__global__ __launch_bounds__(256) void prep_kernel(
    const float* __restrict__ in, uint32_t* __restrict__ st2,
    const int* __restrict__ rows, int* __restrict__ row_start) {
    if (blockIdx.x < CONV_BLOCKS) {
        __shared__ float tile[32][33];
        const int bx = blockIdx.x & 255;     // r-tile
        const int by = blockIdx.x >> 8;      // b-tile
        const int tx = threadIdx.x & 31, ty = threadIdx.x >> 5;  // 32x8
        const int r0 = bx * 32, b0 = by * 32;
#pragma unroll
        for (int j = 0; j < 32; j += 8)
            tile[ty + j][tx] = in[(size_t)(b0 + ty + j) * RES_DIM + r0 + tx];
        __syncthreads();
#pragma unroll
        for (int i = threadIdx.x; i < 512; i += 256) {   // 32 r x 16 pairs
            int rl = i >> 4, pl = i & 15;
            uint32_t lo = f32_to_bf16_rne(tile[2 * pl + 0][rl]);
            uint32_t hi = f32_to_bf16_rne(tile[2 * pl + 1][rl]);
            st2[(size_t)(r0 + rl) * 64 + (b0 >> 1) + pl] = lo | (hi << 16);
        }
    } else {
        const int t  = (blockIdx.x - CONV_BLOCKS) * 256 + threadIdx.x;
        const int k4 = t * 4;
        if (k4 >= NNZ) return;
        if (k4 + 4 <= NNZ) {                 // full int4 (NNZ % 4 == 1)
            const int4 R = *(const int4*)(rows + k4);
            if (k4 == 0)
                for (int r = 0; r <= R.x; ++r) row_start[r] = 0;
            const int rn = rows[k4 + 4];
            for (int r = R.x + 1; r <= R.y; ++r) row_start[r] = k4 + 1;
            for (int r = R.y + 1; r <= R.z; ++r) row_start[r] = k4 + 2;
            for (int r = R.z + 1; r <= R.w; ++r) row_start[r] = k4 + 3;
            for (int r = R.w + 1; r <= rn;  ++r) row_start[r] = k4 + 4;
        } else {                             // k4 == NNZ-1 exactly
            const int r1 = rows[k4];
            for (int r = r1 + 1; r <= RES_DIM; ++r) row_start[r] = NNZ;
        }
    }
}

// ---------------------------------------------------------------------------
// Kernel 2: spmm. 2 rows per block, 2 waves per row. Within a wave, 16-lane
// group g owns 4 contiguous nnz (one int4/float4 broadcast pack load); lane
// j = l&15 holds batches 8j..8j+7 (one uint4 = 8 bf16 per gather; 4 nnz per
// gather instruction). Inner loop is 2-stage software-pipelined: next pack's
// cols/vals AND its 4 gathers are issued before consuming the current
// fragments, so FMAs hide load latency. launch_bounds(256,4) leaves 128
// VGPRs so both pipeline stages (8 uint4 + 8 acc + packs) stay in registers.
// ---------------------------------------------------------------------------
#define FMA8(G, v)                                              \
    do {                                                        \
        a0 = fmaf(v, __uint_as_float((G).x << 16), a0);         \
        a1 = fmaf(v, __uint_as_float((G).x & 0xffff0000u), a1); \
        a2 = fmaf(v, __uint_as_float((G).y << 16), a2);         \
        a3 = fmaf(v, __uint_as_float((G).y & 0xffff0000u), a3); \
        a4 = fmaf(v, __uint_as_float((G).z << 16), a4);         \
        a5 = fmaf(v, __uint_as_float((G).z & 0xffff0000u), a5); \
        a6 = fmaf(v, __uint_as_float((G).w << 16), a6);         \
        a7 = fmaf(v, __uint_as_float((G).w & 0xffff0000u), a7); \
    } while (0)

template <int BF16Y>
__global__ __launch_bounds__(256, 4) void spmm_kernel(
    const float* __restrict__ vals, const int* __restrict__ cols,
    const int* __restrict__ row_start, const uint32_t* __restrict__ st2,
    void* __restrict__ yT) {
    const int t  = threadIdx.x;
    const int w  = t >> 6;         // wave 0..3
    const int rw = w >> 1;         // row within block (0,1)
    const int wr = w & 1;          // wave within row (0,1)
    const int l  = t & 63;
    const int g  = l >> 4;         // 4-nnz pack slot within a 16-nnz unit
    const int j  = l & 15;         // batch slot: batches 8j..8j+7
    // XCD-bijective swizzle over 4096 blocks (4096 % 8 == 0)
    const int bp = (blockIdx.x & 7) * (RES_DIM / 16) + (blockIdx.x >> 3);
    const int r  = bp * 2 + rw;

    const int ks = row_start[r];
    const int ke = row_start[r + 1];
    const int ka = min(ke, (ks + 3) & ~3);   // 16B-align start for int4 loads
    const int U  = (ke - ka) >> 4;           // full 16-nnz units
    const int ts = ka + (U << 4);            // tail start (<16 left)

    const char* stb = (const char*)st2;
    const uint32_t joff = (uint32_t)j << 4;  // byte offset of this lane's 16B
    float a0 = 0, a1 = 0, a2 = 0, a3 = 0, a4 = 0, a5 = 0, a6 = 0, a7 = 0;

    // head (<=3 nnz, unaligned) on wave 0 of the row
    if (wr == 0 && ks < ka) {
        const int kk = ks + g;
        int c = 0; float v = 0.0f;
        if (kk < ka) { c = cols[kk]; v = vals[kk]; }
        const uint4 G = *(const uint4*)(stb + (((uint32_t)c << 8) + joff));
        FMA8(G, v);
    }
    // tail (<=15 nnz) on wave 1 of the row
    if (wr == 1 && ts < ke) {
#pragma unroll
        for (int i = 0; i < 4; ++i) {
            const int kk = ts + 4 * i + g;
            int c = 0; float v = 0.0f;
            if (kk < ke) { c = cols[kk]; v = vals[kk]; }
            const uint4 G = *(const uint4*)(stb + (((uint32_t)c << 8) + joff));
            FMA8(G, v);
        }
    }

    // main units: wave wr takes units wr, wr+2, ... ; 2-stage pipeline
    int u = wr;
    int4 C; float4 V; uint4 G0, G1, G2, G3;
    if (u < U) {
        const int base = ka + (u << 4) + 4 * g;
        C = *(const int4*)(cols + base);
        V = *(const float4*)(vals + base);
        G0 = *(const uint4*)(stb + (((uint32_t)C.x << 8) + joff));
        G1 = *(const uint4*)(stb + (((uint32_t)C.y << 8) + joff));
        G2 = *(const uint4*)(stb + (((uint32_t)C.z << 8) + joff));
        G3 = *(const uint4*)(stb + (((uint32_t)C.w << 8) + joff));
    }
    while (u < U) {
        const int un = u + 2;
        int4 Cn; float4 Vn; uint4 H0, H1, H2, H3;
        if (un < U) {                      // wave-uniform branch
            const int base = ka + (un << 4) + 4 * g;
            Cn = *(const int4*)(cols + base);
            Vn = *(const float4*)(vals + base);
            H0 = *(const uint4*)(stb + (((uint32_t)Cn.x << 8) + joff));
            H1 = *(const uint4*)(stb + (((uint32_t)Cn.y << 8) + joff));
            H2 = *(const uint4*)(stb + (((uint32_t)Cn.z << 8) + joff));
            H3 = *(const uint4*)(stb + (((uint32_t)Cn.w << 8) + joff));
        }
        FMA8(G0, V.x);
        FMA8(G1, V.y);
        FMA8(G2, V.z);
        FMA8(G3, V.w);
        u = un;
        C = Cn; V = Vn; G0 = H0; G1 = H1; G2 = H2; G3 = H3;
    }

    // combine the 4 nnz-groups within the wave
    a0 += __shfl_xor(a0, 16, 64); a0 += __shfl_xor(a0, 32, 64);
    a1 += __shfl_xor(a1, 16, 64); a1 += __shfl_xor(a1, 32, 64);
    a2 += __shfl_xor(a2, 16, 64); a2 += __shfl_xor(a2, 32, 64);
    a3 += __shfl_xor(a3, 16, 64); a3 += __shfl_xor(a3, 32, 64);
    a4 += __shfl_xor(a4, 16, 64); a4 += __shfl_xor(a4, 32, 64);
    a5 += __shfl_xor(a5, 16, 64); a5 += __shfl_xor(a5, 32, 64);
    a6 += __shfl_xor(a6, 16, 64); a6 += __shfl_xor(a6, 32, 64);
    a7 += __shfl_xor(a7, 16, 64); a7 += __shfl_xor(a7, 32, 64);

    // combine the 2 waves of each row via LDS
    __shared__ float red[2][2][16][8];
    if (l < 16) {
        *(float4*)&red[rw][wr][j][0] = make_float4(a0, a1, a2, a3);
        *(float4*)&red[rw][wr][j][4] = make_float4(a4, a5, a6, a7);
    }
    __syncthreads();
    {
        const int rowsel = t >> 7;       // 0,1
        const int b  = t & 127;          // batch
        const int jj = b >> 3, ii = b & 7;
        const int ro = bp * 2 + rowsel;
        float s = red[rowsel][0][jj][ii] + red[rowsel][1][jj][ii];
        if (BF16Y) {
            float shi = __shfl_down(s, 1, 64);   // pairs stay within a wave
            if (!(b & 1))
                ((uint32_t*)yT)[(size_t)ro * 64 + (b >> 1)] =
                    f32_to_bf16_rne(s) | (f32_to_bf16_rne(shi) << 16);
        } else {
            ((float*)yT)[(size_t)ro * BATCH + b] = s;
        }
    }
}

// ---------------------------------------------------------------------------
// Kernel 3: epilogue, 64r x 32b tiles, float4 everywhere.
//   out[b][r] = LEAK*tanh(yT[r][b] + proj[b][r] + BIAS) + (1-LEAK)*res[b][r]
// ---------------------------------------------------------------------------
template <int BF16Y>
__global__ __launch_bounds__(256) void epi_kernel(
    const void* __restrict__ yT, const float* __restrict__ proj,
    const float* __restrict__ res, float* __restrict__ out) {
    __shared__ float tile[64][33];
    const int r0 = blockIdx.x * 64;
    const int b0 = blockIdx.y * 32;
    const int t  = threadIdx.x;
#pragma unroll
    for (int p = 0; p < 2; ++p) {            // load 32 r per pass
        const int rl = p * 32 + (t >> 3);
        const int bq = (t & 7) * 4;
        float x, y, z, wv;
        if (BF16Y) {
            ushort4 u = *(const ushort4*)((const uint16_t*)yT +
                         (size_t)(r0 + rl) * BATCH + b0 + bq);
            x  = __uint_as_float((uint32_t)u.x << 16);
            y  = __uint_as_float((uint32_t)u.y << 16);
            z  = __uint_as_float((uint32_t)u.z << 16);
            wv = __uint_as_float((uint32_t)u.w << 16);
        } else {
            float4 v = *(const float4*)((const float*)yT +
                         (size_t)(r0 + rl) * BATCH + b0 + bq);
            x = v.x; y = v.y; z = v.z; wv = v.w;
        }
        tile[rl][bq + 0] = x; tile[rl][bq + 1] = y;
        tile[rl][bq + 2] = z; tile[rl][bq + 3] = wv;
    }
    __syncthreads();
#pragma unroll
    for (int p = 0; p < 2; ++p) {            // store 16 b per pass
        const int bl = p * 16 + (t >> 4);
        const int rq = (t & 15) * 4;
        const size_t oi = (size_t)(b0 + bl) * RES_DIM + r0 + rq;
        const float4 pj = *(const float4*)(proj + oi);
        const float4 rs = *(const float4*)(res + oi);
        float4 o;
        o.x = LEAK * fast_tanh(tile[rq + 0][bl] + pj.x + BIAS) + (1.0f - LEAK) * rs.x;
        o.y = LEAK * fast_tanh(tile[rq + 1][bl] + pj.y + BIAS) + (1.0f - LEAK) * rs.y;
        o.z = LEAK * fast_tanh(tile[rq + 2][bl] + pj.z + BIAS) + (1.0f - LEAK) * rs.z;
        o.w = LEAK * fast_tanh(tile[rq + 3][bl] + pj.w + BIAS) + (1.0f - LEAK) * rs.w;
        *(float4*)(out + oi) = o;
    }
}

// ---------------------------------------------------------------------------
extern "C" void kernel_launch(void* const* d_in, const int* in_sizes, int n_in,
                              void* d_out, int out_size, void* d_ws, size_t ws_size,
                              hipStream_t stream) {
    const float* proj      = (const float*)d_in[0];
    const float* res_state = (const float*)d_in[1];
    const float* wr_vals   = (const float*)d_in[2];
    const int*   wr_rows   = (const int*)d_in[3];
    const int*   wr_cols   = (const int*)d_in[4];
    float*       out       = (float*)d_out;

    // ws layout: st2 (2 MB) | row_start (32.8 KB) | yT (4 MB f32 or 2 MB bf16)
    uint8_t*  ws        = (uint8_t*)d_ws;
    uint32_t* st2       = (uint32_t*)ws;
    int*      row_start = (int*)(ws + 2097152);
    uint8_t*  yT        = ws + 2130176;
    const bool f32y = ws_size >= (2130176ull + (size_t)RES_DIM * BATCH * 4);

    prep_kernel<<<CONV_BLOCKS + BND_BLOCKS, 256, 0, stream>>>(
        res_state, st2, wr_rows, row_start);

    if (f32y) {
        spmm_kernel<0><<<RES_DIM / 2, 256, 0, stream>>>(wr_vals, wr_cols, row_start, st2, yT);
        epi_kernel<0><<<dim3(RES_DIM / 64, BATCH / 32), 256, 0, stream>>>(yT, proj, res_state, out);
    } else {
        spmm_kernel<1><<<RES_DIM / 2, 256, 0, stream>>>(wr_vals, wr_cols, row_start, st2, yT);
        epi_kernel<1><<<dim3(RES_DIM / 64, BATCH / 32), 256, 0, stream>>>(yT, proj, res_state, out);
    }
}